// Round 3
// baseline (7681.143 us; speedup 1.0000x reference)
//
#include <hip/hip_runtime.h>
#include <math.h>

#define TT 256
#define BB 128
#define II 512
#define HH 1024
#define NCLS 1000
#define NBLK 64           // persistent blocks
#define CPB 16            // h-cols per block

typedef __bf16 bf16;
typedef bf16 bf16x8 __attribute__((ext_vector_type(8)));
typedef float f32x4 __attribute__((ext_vector_type(4)));

#define AT_LD_U64(p) __hip_atomic_load((p), __ATOMIC_RELAXED, __HIP_MEMORY_SCOPE_AGENT)
#define AT_LD_I32(p) __hip_atomic_load((p), __ATOMIC_RELAXED, __HIP_MEMORY_SCOPE_AGENT)
#define AT_ST_U32(p, v) __hip_atomic_store((p), (v), __ATOMIC_RELAXED, __HIP_MEMORY_SCOPE_AGENT)
#define AT_ST_I32(p, v) __hip_atomic_store((p), (v), __ATOMIC_RELAXED, __HIP_MEMORY_SCOPE_AGENT)

// ---------------- ws layout (bytes) ----------------
#define OFF_WHPK   0u            // 64*48*1024*2 = 6,291,456
#define OFF_WXPK   6291456u      // 64*64*512*2  = 4,194,304
#define OFF_BIAS   10485760u     // 16,384
#define OFF_HB0    10502144u     // 262,144
#define OFF_HB1    10764288u     // 262,144
#define OFF_FLAGS  11026432u     // 4,096
#define OFF_LG     11030528u     // 512,000
#define OFF_XB     11542528u     // 33,554,432 (optional)
#define WS_BIG     45096960u

// ---------------- init: zero h0 and flags ----------------
__global__ void init_state(bf16* __restrict__ h0, int* __restrict__ flags) {
    int idx = blockIdx.x * 256 + threadIdx.x;
    if (idx < BB * HH) h0[idx] = (bf16)0.0f;
    if (idx < NBLK) flags[idx] = 0;
}

// ---------------- pack W_h -> WhPK[bid][g*16+c][k], g in {f,i,o} ----------------
__global__ void pack_wh(const float* __restrict__ Wfh, const float* __restrict__ Wih,
                        const float* __restrict__ Woh, bf16* __restrict__ WhPK) {
    int blk = blockIdx.x;                 // 3 * 16 * 16
    int g = blk / 256, rem = blk % 256;
    int ht = rem / 16, kt = rem % 16;
    const float* src = (g == 0) ? Wfh : (g == 1) ? Wih : Woh;
    __shared__ bf16 tile[64][72];
    int tid = threadIdx.x;
    for (int i = tid; i < 4096; i += 256) {
        int kr = i >> 6, hc = i & 63;
        tile[kr][hc] = (bf16)src[(size_t)(kt * 64 + kr) * HH + ht * 64 + hc];
    }
    __syncthreads();
    for (int i = tid; i < 4096; i += 256) {
        int hc = i >> 6, kr = i & 63;
        int h = ht * 64 + hc, bid = h >> 4, c = h & 15;
        WhPK[((size_t)bid * 48 + g * 16 + c) * 1024 + kt * 64 + kr] = tile[kr][hc];
    }
}

// ---------------- pack W_x -> WxPK[bid][g*16+c][k], g in {f,i,o,c} ----------------
__global__ void pack_wx(const float* __restrict__ Wfx, const float* __restrict__ Wix,
                        const float* __restrict__ Wox, const float* __restrict__ Wcx,
                        bf16* __restrict__ WxPK) {
    int blk = blockIdx.x;                 // 4 * 16 * 8
    int g = blk / 128, rem = blk % 128;
    int ht = rem / 8, kt = rem % 8;
    const float* src = (g == 0) ? Wfx : (g == 1) ? Wix : (g == 2) ? Wox : Wcx;
    __shared__ bf16 tile[64][72];
    int tid = threadIdx.x;
    for (int i = tid; i < 4096; i += 256) {
        int kr = i >> 6, hc = i & 63;
        tile[kr][hc] = (bf16)src[(size_t)(kt * 64 + kr) * HH + ht * 64 + hc];
    }
    __syncthreads();
    for (int i = tid; i < 4096; i += 256) {
        int hc = i >> 6, kr = i & 63;
        int h = ht * 64 + hc, bid = h >> 4, c = h & 15;
        WxPK[((size_t)bid * 64 + g * 16 + c) * 512 + kt * 64 + kr] = tile[kr][hc];
    }
}

__global__ void pack_bias(const float* __restrict__ bf_, const float* __restrict__ bi_,
                          const float* __restrict__ bo_, const float* __restrict__ bc_,
                          float* __restrict__ bias) {
    int i = blockIdx.x * 256 + threadIdx.x;
    if (i < 4 * HH) {
        int g = i >> 10, hn = i & 1023;
        const float* b = (g == 0) ? bf_ : (g == 1) ? bi_ : (g == 2) ? bo_ : bc_;
        bias[i] = b[hn];
    }
}

// ---------------- x -> bf16 (optional fast path) ----------------
__global__ void conv_x(const float* __restrict__ x, bf16* __restrict__ xb) {
    size_t i = ((size_t)blockIdx.x * 256 + threadIdx.x) * 8;
    float4 f0 = *(const float4*)(x + i);
    float4 f1 = *(const float4*)(x + i + 4);
    bf16x8 v;
    v[0]=(bf16)f0.x; v[1]=(bf16)f0.y; v[2]=(bf16)f0.z; v[3]=(bf16)f0.w;
    v[4]=(bf16)f1.x; v[5]=(bf16)f1.y; v[6]=(bf16)f1.z; v[7]=(bf16)f1.w;
    *(bf16x8*)(xb + i) = v;
}

__device__ __forceinline__ float sigm(float x) {
    return 1.0f / (1.0f + __expf(-x));
}
__device__ __forceinline__ float tanh_f(float x) {
    float e = __expf(-2.0f * fabsf(x));       // <= 1, no overflow
    float t = (1.0f - e) / (1.0f + e);
    return copysignf(t, x);
}

// ---------------- persistent recurrent kernel ----------------
// 64 blocks x 256 threads (4 waves, m=2). Block owns h-cols [bid*16, bid*16+16).
// Gates are 4 separate 16-col MFMA n-tiles (tau=0..3 = f,i,o,c) -> pointwise
// is fully thread-local. Wh (f,i,o; 48 rows x 1024 k) in 96KB LDS, XOR-swizzled.
// Cross-XCD h/flag exchange via relaxed AGENT-scope atomics (sc0 sc1), no fences.
template<bool XB>
__global__ __launch_bounds__(256, 1) void lstm_persist(
    const float* __restrict__ xf, const bf16* __restrict__ xbb,
    const bf16* __restrict__ WhPK, const bf16* __restrict__ WxPK,
    const float* __restrict__ bias,
    bf16* __restrict__ hb0, bf16* __restrict__ hb1,
    int* __restrict__ flags) {
    extern __shared__ char lds[];
    const int tid = threadIdx.x, wave = tid >> 6, lane = tid & 63;
    const int bid = blockIdx.x, n0 = bid * CPB;

    // ---- stage Wh slice into LDS (48 rows x 2048B, swizzle ^((r&15)<<4)) ----
    for (int i = tid; i < 48 * 128; i += 256) {
        int r = i >> 7, c8 = i & 127;
        bf16x8 v = *(const bf16x8*)(WhPK + ((size_t)bid * 48 + r) * 1024 + c8 * 8);
        int byte = (r * 2048 + c8 * 16) ^ ((r & 15) << 4);
        *(bf16x8*)(lds + byte) = v;
    }
    __syncthreads();

    const int lr = lane & 15;            // A-row / B-col within 16-tile
    const int lk = (lane >> 4) * 8;      // k offset within 32-chunk
    const int hcol = n0 + lr;
    const int rb = (lane >> 4) * 4;      // D row base within 16-tile
    const float bbf = bias[0 * HH + hcol];
    const float bbi = bias[1 * HH + hcol];
    const float bbo = bias[2 * HH + hcol];
    const float bbc = bias[3 * HH + hcol];
    float creg[2][4] = {};               // c-state, fully register-resident

    for (int t = 0; t < TT; ++t) {
        f32x4 acc[2][4] = {};            // [m][tau]

        // ---- x-part (K=512), independent of h_t: hides sync latency ----
        #pragma unroll 4
        for (int kk = 0; kk < 16; ++kk) {
            const int k0 = kk * 32 + lk;
            bf16x8 a0, a1;
            if (XB) {
                a0 = *(const bf16x8*)(xbb + ((size_t)(wave * 32 + lr) * TT + t) * II + k0);
                a1 = *(const bf16x8*)(xbb + ((size_t)(wave * 32 + 16 + lr) * TT + t) * II + k0);
            } else {
                const float* s0 = xf + ((size_t)(wave * 32 + lr) * TT + t) * II + k0;
                const float* s1 = xf + ((size_t)(wave * 32 + 16 + lr) * TT + t) * II + k0;
                float4 f0 = *(const float4*)s0, f1 = *(const float4*)(s0 + 4);
                float4 g0 = *(const float4*)s1, g1 = *(const float4*)(s1 + 4);
                a0[0]=(bf16)f0.x; a0[1]=(bf16)f0.y; a0[2]=(bf16)f0.z; a0[3]=(bf16)f0.w;
                a0[4]=(bf16)f1.x; a0[5]=(bf16)f1.y; a0[6]=(bf16)f1.z; a0[7]=(bf16)f1.w;
                a1[0]=(bf16)g0.x; a1[1]=(bf16)g0.y; a1[2]=(bf16)g0.z; a1[3]=(bf16)g0.w;
                a1[4]=(bf16)g1.x; a1[5]=(bf16)g1.y; a1[6]=(bf16)g1.z; a1[7]=(bf16)g1.w;
            }
            #pragma unroll
            for (int tau = 0; tau < 4; ++tau) {
                bf16x8 b = *(const bf16x8*)(WxPK + ((size_t)bid * 64 + tau * 16 + lr) * 512 + k0);
                acc[0][tau] = __builtin_amdgcn_mfma_f32_16x16x32_bf16(a0, b, acc[0][tau], 0, 0, 0);
                acc[1][tau] = __builtin_amdgcn_mfma_f32_16x16x32_bf16(a1, b, acc[1][tau], 0, 0, 0);
            }
        }

        // ---- wait for h_t: every wave polls all 64 producer flags ----
        {
            while (true) {
                int v = AT_LD_I32(&flags[lane]);
                if (__all(v >= t)) break;
                __builtin_amdgcn_s_sleep(1);
            }
            asm volatile("" ::: "memory");   // no reordering of h loads above the poll
        }

        // ---- h-part (K=1024), coherent 8B loads (sc0 sc1, L2-bypass) ----
        const bf16* hin = (t & 1) ? hb1 : hb0;
        #pragma unroll 8
        for (int kk = 0; kk < 32; ++kk) {
            const int k0 = kk * 32 + lk;
            const unsigned long long* p0 =
                (const unsigned long long*)(hin + (size_t)(wave * 32 + lr) * HH + k0);
            const unsigned long long* p1 =
                (const unsigned long long*)(hin + (size_t)(wave * 32 + 16 + lr) * HH + k0);
            union { unsigned long long u[2]; bf16x8 v; } A0, A1;
            A0.u[0] = AT_LD_U64(p0); A0.u[1] = AT_LD_U64(p0 + 1);
            A1.u[0] = AT_LD_U64(p1); A1.u[1] = AT_LD_U64(p1 + 1);
            #pragma unroll
            for (int tau = 0; tau < 3; ++tau) {        // c-gate: x-only, skip
                const int r = tau * 16 + lr;
                bf16x8 b = *(const bf16x8*)(lds + ((r * 2048 + k0 * 2) ^ ((r & 15) << 4)));
                acc[0][tau] = __builtin_amdgcn_mfma_f32_16x16x32_bf16(A0.v, b, acc[0][tau], 0, 0, 0);
                acc[1][tau] = __builtin_amdgcn_mfma_f32_16x16x32_bf16(A1.v, b, acc[1][tau], 0, 0, 0);
            }
        }

        // ---- pointwise (thread-local), h store as paired 4B coherent words ----
        bf16* hout = (t & 1) ? hb0 : hb1;
        const int hcol0 = n0 + (lr & 14);
        #pragma unroll
        for (int m = 0; m < 2; ++m) {
            #pragma unroll
            for (int j = 0; j < 4; ++j) {
                const int row = wave * 32 + m * 16 + rb + j;
                float pf = acc[m][0][j] + bbf;
                float pi = acc[m][1][j] + bbi;
                float po = acc[m][2][j] + bbo;
                float pc = acc[m][3][j] + bbc;
                float fg = sigm(pf), ig = sigm(pi), og = sigm(po);
                float cn = tanh_f(pc) * ig + creg[m][j] * fg;
                creg[m][j] = cn;
                union { bf16 h; unsigned short u; } cv;
                cv.h = (bf16)(tanh_f(cn) * og);
                unsigned int mine  = (unsigned int)cv.u;
                unsigned int other = (unsigned int)__shfl_xor((int)mine, 1);
                if (!(lane & 1)) {
                    unsigned int word = mine | (other << 16);
                    AT_ST_U32((unsigned int*)(hout + (size_t)row * HH + hcol0), word);
                }
            }
        }
        __syncthreads();                  // implies s_waitcnt vmcnt(0): h stores done
        if (tid == 0) AT_ST_I32(&flags[bid], t + 1);
    }
}

// ---------------- head: logits = h @ W_ph + b_p ----------------
__global__ __launch_bounds__(256) void logits_kernel(
    const bf16* __restrict__ h, const float* __restrict__ Wp,
    const float* __restrict__ bp, float* __restrict__ out) {
    const int tid = threadIdx.x;
    const int r0  = blockIdx.x * 8;
    __shared__ float hs[8][HH];
    for (int i = tid; i < 8 * HH; i += 256)
        hs[i >> 10][i & 1023] = (float)h[(size_t)(r0 + (i >> 10)) * HH + (i & 1023)];
    __syncthreads();
    float acc[8][4] = {};
    for (int k = 0; k < HH; ++k) {
        float w[4];
        #pragma unroll
        for (int m = 0; m < 4; ++m) {
            int cc = tid + 256 * m;
            w[m] = (cc < NCLS) ? Wp[(size_t)k * NCLS + cc] : 0.0f;
        }
        #pragma unroll
        for (int r = 0; r < 8; ++r) {
            float hv = hs[r][k];
            #pragma unroll
            for (int m = 0; m < 4; ++m) acc[r][m] += hv * w[m];
        }
    }
    #pragma unroll
    for (int r = 0; r < 8; ++r) {
        #pragma unroll
        for (int m = 0; m < 4; ++m) {
            int cc = tid + 256 * m;
            if (cc < NCLS) out[(size_t)(r0 + r) * NCLS + cc] = acc[r][m] + bp[cc];
        }
    }
}

// ---------------- softmax over C=1000 per row ----------------
__global__ __launch_bounds__(256) void softmax_kernel(const float* __restrict__ logits,
                                                      float* __restrict__ out) {
    const int b = blockIdx.x, tid = threadIdx.x;
    __shared__ float red[256];
    float v[4];
    float mx = -1e30f;
    #pragma unroll
    for (int m = 0; m < 4; ++m) {
        int cc = tid + 256 * m;
        v[m] = (cc < NCLS) ? logits[(size_t)b * NCLS + cc] : -1e30f;
        mx = fmaxf(mx, v[m]);
    }
    red[tid] = mx; __syncthreads();
    for (int s = 128; s > 0; s >>= 1) {
        if (tid < s) red[tid] = fmaxf(red[tid], red[tid + s]);
        __syncthreads();
    }
    mx = red[0]; __syncthreads();
    float sum = 0.0f;
    #pragma unroll
    for (int m = 0; m < 4; ++m) {
        int cc = tid + 256 * m;
        if (cc < NCLS) { v[m] = __expf(v[m] - mx); sum += v[m]; }
    }
    red[tid] = sum; __syncthreads();
    for (int s = 128; s > 0; s >>= 1) {
        if (tid < s) red[tid] += red[tid + s];
        __syncthreads();
    }
    float inv = 1.0f / red[0];
    #pragma unroll
    for (int m = 0; m < 4; ++m) {
        int cc = tid + 256 * m;
        if (cc < NCLS) out[(size_t)b * NCLS + cc] = v[m] * inv;
    }
}

extern "C" void kernel_launch(void* const* d_in, const int* in_sizes, int n_in,
                              void* d_out, int out_size, void* d_ws, size_t ws_size,
                              hipStream_t stream) {
    const float* x   = (const float*)d_in[0];
    const float* Wfx = (const float*)d_in[1];
    const float* Wfh = (const float*)d_in[2];
    const float* bf_ = (const float*)d_in[3];
    const float* Wix = (const float*)d_in[4];
    const float* Wih = (const float*)d_in[5];
    const float* bi_ = (const float*)d_in[6];
    const float* Wox = (const float*)d_in[7];
    const float* Woh = (const float*)d_in[8];
    const float* bo_ = (const float*)d_in[9];
    const float* Wcx = (const float*)d_in[10];
    const float* bc_ = (const float*)d_in[11];
    const float* Wp  = (const float*)d_in[12];
    const float* bp  = (const float*)d_in[13];

    char* ws = (char*)d_ws;
    bf16*  WhPK = (bf16*)(ws + OFF_WHPK);
    bf16*  WxPK = (bf16*)(ws + OFF_WXPK);
    float* bias = (float*)(ws + OFF_BIAS);
    bf16*  hb0  = (bf16*)(ws + OFF_HB0);
    bf16*  hb1  = (bf16*)(ws + OFF_HB1);
    int*   flags= (int*)(ws + OFF_FLAGS);
    float* lg   = (float*)(ws + OFF_LG);
    bf16*  xb   = (bf16*)(ws + OFF_XB);

    // 96KB dynamic LDS > 64KB default cap; host-side attr set is capture-safe.
    (void)hipFuncSetAttribute((const void*)lstm_persist<true>,
                              hipFuncAttributeMaxDynamicSharedMemorySize, 98304);
    (void)hipFuncSetAttribute((const void*)lstm_persist<false>,
                              hipFuncAttributeMaxDynamicSharedMemorySize, 98304);

    init_state<<<(BB * HH + 255) / 256, 256, 0, stream>>>(hb0, flags);
    pack_wh<<<3 * 16 * 16, 256, 0, stream>>>(Wfh, Wih, Woh, WhPK);
    pack_wx<<<4 * 16 * 8, 256, 0, stream>>>(Wfx, Wix, Wox, Wcx, WxPK);
    pack_bias<<<16, 256, 0, stream>>>(bf_, bi_, bo_, bc_, bias);

    const bool big = (ws_size >= (size_t)WS_BIG);
    if (big) {
        conv_x<<<(BB * TT * II) / (8 * 256), 256, 0, stream>>>(x, xb);
        lstm_persist<true><<<NBLK, 256, 98304, stream>>>(x, xb, WhPK, WxPK, bias,
                                                         hb0, hb1, flags);
    } else {
        lstm_persist<false><<<NBLK, 256, 98304, stream>>>(x, xb, WhPK, WxPK, bias,
                                                          hb0, hb1, flags);
    }

    // T=256 even -> final h in hb0
    logits_kernel<<<BB / 8, 256, 0, stream>>>(hb0, Wp, bp, lg);
    softmax_kernel<<<BB, 256, 0, stream>>>(lg, (float*)d_out);
}

// Round 4
// 6713.004 us; speedup vs baseline: 1.1442x; 1.1442x over previous
//
#include <hip/hip_runtime.h>
#include <math.h>

#define TT 256
#define BB 128
#define II 512
#define HH 1024
#define NCLS 1000
#define NBLK 64           // persistent blocks (= h-col chunks)
#define CPB 16            // h-cols per block

typedef __bf16 bf16;
typedef bf16 bf16x8 __attribute__((ext_vector_type(8)));
typedef float f32x4 __attribute__((ext_vector_type(4)));
typedef int i32x4 __attribute__((ext_vector_type(4)));

#define AT_LD_I32(p) __hip_atomic_load((p), __ATOMIC_RELAXED, __HIP_MEMORY_SCOPE_AGENT)
#define AT_ST_U32(p, v) __hip_atomic_store((p), (v), __ATOMIC_RELAXED, __HIP_MEMORY_SCOPE_AGENT)
#define AT_ST_I32(p, v) __hip_atomic_store((p), (v), __ATOMIC_RELAXED, __HIP_MEMORY_SCOPE_AGENT)

// ---------------- ws layout (bytes) ----------------
#define OFF_WHPK   0u            // 64*48*1024*2 = 6,291,456   (dead after scan)
#define OFF_LG     0u            // logits alias WhPK (post-scan only)
#define OFF_WXPK   6291456u      // 64*64*512*2  = 4,194,304
#define OFF_BIAS   10485760u     // 16,384
#define OFF_HPK0   10502144u     // 262,144   h ping  [chunk][row][16] bf16
#define OFF_HPK1   10764288u     // 262,144   h pong
#define OFF_HFIN   11026432u     // 262,144   final h, row-major [b][1024]
#define OFF_FLAGS  11288576u     // 4,096
#define OFF_XT     11292672u     // 33,554,432  xT[t][b][i] bf16
#define WS_BIG     44847104u

// ---------------- init: zero h0 (hpk0) and flags ----------------
__global__ void init_state(int* __restrict__ hpk0i, int* __restrict__ flags) {
    int idx = blockIdx.x * 256 + threadIdx.x;
    if (idx < 65536) hpk0i[idx] = 0;          // 256 KB of zeros
    if (idx < NBLK) flags[idx] = 0;
}

// ---------------- pack W_h -> WhPK[bid][g*16+c][k], g in {f,i,o} ----------------
__global__ void pack_wh(const float* __restrict__ Wfh, const float* __restrict__ Wih,
                        const float* __restrict__ Woh, bf16* __restrict__ WhPK) {
    int blk = blockIdx.x;                 // 3 * 16 * 16
    int g = blk / 256, rem = blk % 256;
    int ht = rem / 16, kt = rem % 16;
    const float* src = (g == 0) ? Wfh : (g == 1) ? Wih : Woh;
    __shared__ bf16 tile[64][72];
    int tid = threadIdx.x;
    for (int i = tid; i < 4096; i += 256) {
        int kr = i >> 6, hc = i & 63;
        tile[kr][hc] = (bf16)src[(size_t)(kt * 64 + kr) * HH + ht * 64 + hc];
    }
    __syncthreads();
    for (int i = tid; i < 4096; i += 256) {
        int hc = i >> 6, kr = i & 63;
        int h = ht * 64 + hc, bid = h >> 4, c = h & 15;
        WhPK[((size_t)bid * 48 + g * 16 + c) * 1024 + kt * 64 + kr] = tile[kr][hc];
    }
}

// ---------------- pack W_x -> WxPK[bid][g*16+c][k], g in {f,i,o,c} ----------------
__global__ void pack_wx(const float* __restrict__ Wfx, const float* __restrict__ Wix,
                        const float* __restrict__ Wox, const float* __restrict__ Wcx,
                        bf16* __restrict__ WxPK) {
    int blk = blockIdx.x;                 // 4 * 16 * 8
    int g = blk / 128, rem = blk % 128;
    int ht = rem / 8, kt = rem % 8;
    const float* src = (g == 0) ? Wfx : (g == 1) ? Wix : (g == 2) ? Wox : Wcx;
    __shared__ bf16 tile[64][72];
    int tid = threadIdx.x;
    for (int i = tid; i < 4096; i += 256) {
        int kr = i >> 6, hc = i & 63;
        tile[kr][hc] = (bf16)src[(size_t)(kt * 64 + kr) * HH + ht * 64 + hc];
    }
    __syncthreads();
    for (int i = tid; i < 4096; i += 256) {
        int hc = i >> 6, kr = i & 63;
        int h = ht * 64 + hc, bid = h >> 4, c = h & 15;
        WxPK[((size_t)bid * 64 + g * 16 + c) * 512 + kt * 64 + kr] = tile[kr][hc];
    }
}

__global__ void pack_bias(const float* __restrict__ bf_, const float* __restrict__ bi_,
                          const float* __restrict__ bo_, const float* __restrict__ bc_,
                          float* __restrict__ bias) {
    int i = blockIdx.x * 256 + threadIdx.x;
    if (i < 4 * HH) {
        int g = i >> 10, hn = i & 1023;
        const float* b = (g == 0) ? bf_ : (g == 1) ? bi_ : (g == 2) ? bo_ : bc_;
        bias[i] = b[hn];
    }
}

// ---------------- x[b][t][i] fp32 -> xT[t][b][i] bf16 ----------------
__global__ void conv_xT(const float* __restrict__ x, bf16* __restrict__ xT) {
    size_t o = ((size_t)blockIdx.x * 256 + threadIdx.x) * 8;
    int t = (int)(o >> 16);               // / (BB*II = 65536)
    int rem = (int)(o & 65535);
    int b = rem >> 9, i = rem & 511;
    const float* s = x + ((size_t)b * TT + t) * II + i;
    float4 f0 = *(const float4*)(s);
    float4 f1 = *(const float4*)(s + 4);
    bf16x8 v;
    v[0]=(bf16)f0.x; v[1]=(bf16)f0.y; v[2]=(bf16)f0.z; v[3]=(bf16)f0.w;
    v[4]=(bf16)f1.x; v[5]=(bf16)f1.y; v[6]=(bf16)f1.z; v[7]=(bf16)f1.w;
    *(bf16x8*)(xT + o) = v;
}

__device__ __forceinline__ float sigm(float x) {
    return 1.0f / (1.0f + __expf(-x));
}
__device__ __forceinline__ float tanh_f(float x) {
    float e = __expf(-2.0f * fabsf(x));
    float t = (1.0f - e) / (1.0f + e);
    return copysignf(t, x);
}

// ---------------- persistent recurrent kernel ----------------
// 64 blocks x 512 threads (8 waves, m=1 row-tile per wave). Block owns h-cols
// [bid*16, bid*16+16). Gates f,i,o,c = 4 MFMA n-tiles; pointwise thread-local.
// Wh (f,i,o) in 96KB LDS (XOR-swizzled, conflict-free per R3 counters).
// h exchange: producer -> plain sc0 sc1 dword stores into hpk[chunk][row][16];
// consumer -> pipelined inline-asm global_load_dwordx4 sc0 sc1 with counted
// vmcnt (T4). Flags via relaxed AGENT atomics (proven R2/R3).
template<bool XB>
__global__ __launch_bounds__(512, 1) void lstm_persist(
    const float* __restrict__ xf, const bf16* __restrict__ xT,
    const bf16* __restrict__ WhPK, const bf16* __restrict__ WxPK,
    const float* __restrict__ bias,
    bf16* __restrict__ hpk0, bf16* __restrict__ hpk1,
    bf16* __restrict__ hfin, int* __restrict__ flags) {
    extern __shared__ char lds[];
    const int tid = threadIdx.x, w = tid >> 6, lane = tid & 63;
    const int bid = blockIdx.x, n0 = bid * CPB;

    // ---- stage Wh slice into LDS (48 rows x 2048B, swizzle ^((r&15)<<4)) ----
    for (int i = tid; i < 48 * 128; i += 512) {
        int r = i >> 7, c8 = i & 127;
        bf16x8 v = *(const bf16x8*)(WhPK + ((size_t)bid * 48 + r) * 1024 + c8 * 8);
        int byte = (r * 2048 + c8 * 16) ^ ((r & 15) << 4);
        *(bf16x8*)(lds + byte) = v;
    }
    __syncthreads();

    const int lr = lane & 15;            // A-row / B-col index within 16-tile
    const int lkq = lane >> 4;
    const int lk = lkq * 8;              // k offset within 32-chunk
    const int row = w * 16 + lr;         // A row this lane loads (x and h)
    const int hcol = n0 + lr;
    const int rb = lkq * 4;              // D row base within 16-tile
    const float bbf = bias[0 * HH + hcol];
    const float bbi = bias[1 * HH + hcol];
    const float bbo = bias[2 * HH + hcol];
    const float bbc = bias[3 * HH + hcol];
    float creg[4] = {0.f, 0.f, 0.f, 0.f};
    // lane's byte offset into hpk for kk=0: chunk=(2kk+(lk>>4)), col=(lk&8)
    const int hvoff = ((lk >> 4) * 128 + row) * 32 + (lk & 8) * 2;

    for (int t = 0; t < TT; ++t) {
        f32x4 acc[4] = {};               // f,i,o,c

        // ---- x-part (K=512), independent of h_t ----
        #pragma unroll 4
        for (int kk = 0; kk < 16; ++kk) {
            const int k0 = kk * 32 + lk;
            bf16x8 a;
            if (XB) {
                a = *(const bf16x8*)(xT + ((size_t)t * BB + row) * II + k0);
            } else {
                const float* s = xf + ((size_t)row * TT + t) * II + k0;
                float4 f0 = *(const float4*)s, f1 = *(const float4*)(s + 4);
                a[0]=(bf16)f0.x; a[1]=(bf16)f0.y; a[2]=(bf16)f0.z; a[3]=(bf16)f0.w;
                a[4]=(bf16)f1.x; a[5]=(bf16)f1.y; a[6]=(bf16)f1.z; a[7]=(bf16)f1.w;
            }
            #pragma unroll
            for (int tau = 0; tau < 4; ++tau) {
                bf16x8 b = *(const bf16x8*)(WxPK + ((size_t)bid * 64 + tau * 16 + lr) * 512 + k0);
                acc[tau] = __builtin_amdgcn_mfma_f32_16x16x32_bf16(a, b, acc[tau], 0, 0, 0);
            }
        }

        // ---- wait for h_t ----
        if (w == 0) {
            while (true) {
                int v = AT_LD_I32(&flags[lane]);
                if (__all(v >= t)) break;
                __builtin_amdgcn_s_sleep(1);
            }
        }
        __syncthreads();
        asm volatile("s_waitcnt vmcnt(0)" ::: "memory");
        __builtin_amdgcn_sched_barrier(0);

        // ---- h-part: 32 pipelined coherent dwordx4 loads, counted drains ----
        const char* hbase = (const char*)((t & 1) ? hpk1 : hpk0);
        i32x4 hv[32];
        #pragma unroll
        for (int kk = 0; kk < 32; ++kk) {
            const void* p = hbase + hvoff + kk * 8192;
            asm volatile("global_load_dwordx4 %0, %1, off sc0 sc1"
                         : "=v"(hv[kk]) : "v"(p) : "memory");
        }
        #pragma unroll
        for (int c = 0; c < 4; ++c) {
            if (c == 0)      asm volatile("s_waitcnt vmcnt(24)" ::: "memory");
            else if (c == 1) asm volatile("s_waitcnt vmcnt(16)" ::: "memory");
            else if (c == 2) asm volatile("s_waitcnt vmcnt(8)"  ::: "memory");
            else             asm volatile("s_waitcnt vmcnt(0)"  ::: "memory");
            __builtin_amdgcn_sched_barrier(0);
            #pragma unroll
            for (int kk = c * 8; kk < c * 8 + 8; ++kk) {
                const int k0 = kk * 32 + lk;
                bf16x8 a = __builtin_bit_cast(bf16x8, hv[kk]);
                #pragma unroll
                for (int tau = 0; tau < 3; ++tau) {       // c-gate: x-only
                    const int r = tau * 16 + lr;
                    bf16x8 b = *(const bf16x8*)(lds + ((r * 2048 + k0 * 2) ^ ((r & 15) << 4)));
                    acc[tau] = __builtin_amdgcn_mfma_f32_16x16x32_bf16(a, b, acc[tau], 0, 0, 0);
                }
            }
            __builtin_amdgcn_sched_barrier(0);
        }

        // ---- pointwise (thread-local), h_{t+1} -> hpk[(t+1)&1] ----
        bf16* hout = (t & 1) ? hpk0 : hpk1;
        #pragma unroll
        for (int j = 0; j < 4; ++j) {
            const int row_o = w * 16 + rb + j;
            float pf = acc[0][j] + bbf;
            float pi = acc[1][j] + bbi;
            float po = acc[2][j] + bbo;
            float pc = acc[3][j] + bbc;
            float fg = sigm(pf), ig = sigm(pi), og = sigm(po);
            float cn = tanh_f(pc) * ig + creg[j] * fg;
            creg[j] = cn;
            float hv_f = tanh_f(cn) * og;
            union { bf16 h; unsigned short u; } cv;
            cv.h = (bf16)hv_f;
            unsigned int mine  = (unsigned int)cv.u;
            unsigned int other = (unsigned int)__shfl_xor((int)mine, 1);
            if (!(lane & 1)) {
                unsigned int word = mine | (other << 16);
                AT_ST_U32((unsigned int*)(hout + ((size_t)bid * 128 + row_o) * 16 + (lr & 14)), word);
            }
            if (t == TT - 1) hfin[(size_t)row_o * HH + hcol] = cv.h;  // normal store
        }
        __syncthreads();                  // drains stores (vmcnt 0) before flag
        if (tid == 0) AT_ST_I32(&flags[bid], t + 1);
    }
}

// ---------------- head: logits = h @ W_ph + b_p ----------------
__global__ __launch_bounds__(256) void logits_kernel(
    const bf16* __restrict__ h, const float* __restrict__ Wp,
    const float* __restrict__ bp, float* __restrict__ out) {
    const int tid = threadIdx.x;
    const int r0  = blockIdx.x * 8;
    __shared__ float hs[8][HH];
    for (int i = tid; i < 8 * HH; i += 256)
        hs[i >> 10][i & 1023] = (float)h[(size_t)(r0 + (i >> 10)) * HH + (i & 1023)];
    __syncthreads();
    float acc[8][4] = {};
    for (int k = 0; k < HH; ++k) {
        float w[4];
        #pragma unroll
        for (int m = 0; m < 4; ++m) {
            int cc = tid + 256 * m;
            w[m] = (cc < NCLS) ? Wp[(size_t)k * NCLS + cc] : 0.0f;
        }
        #pragma unroll
        for (int r = 0; r < 8; ++r) {
            float hv = hs[r][k];
            #pragma unroll
            for (int m = 0; m < 4; ++m) acc[r][m] += hv * w[m];
        }
    }
    #pragma unroll
    for (int r = 0; r < 8; ++r) {
        #pragma unroll
        for (int m = 0; m < 4; ++m) {
            int cc = tid + 256 * m;
            if (cc < NCLS) out[(size_t)(r0 + r) * NCLS + cc] = acc[r][m] + bp[cc];
        }
    }
}

// ---------------- softmax over C=1000 per row ----------------
__global__ __launch_bounds__(256) void softmax_kernel(const float* __restrict__ logits,
                                                      float* __restrict__ out) {
    const int b = blockIdx.x, tid = threadIdx.x;
    __shared__ float red[256];
    float v[4];
    float mx = -1e30f;
    #pragma unroll
    for (int m = 0; m < 4; ++m) {
        int cc = tid + 256 * m;
        v[m] = (cc < NCLS) ? logits[(size_t)b * NCLS + cc] : -1e30f;
        mx = fmaxf(mx, v[m]);
    }
    red[tid] = mx; __syncthreads();
    for (int s = 128; s > 0; s >>= 1) {
        if (tid < s) red[tid] = fmaxf(red[tid], red[tid + s]);
        __syncthreads();
    }
    mx = red[0]; __syncthreads();
    float sum = 0.0f;
    #pragma unroll
    for (int m = 0; m < 4; ++m) {
        int cc = tid + 256 * m;
        if (cc < NCLS) { v[m] = __expf(v[m] - mx); sum += v[m]; }
    }
    red[tid] = sum; __syncthreads();
    for (int s = 128; s > 0; s >>= 1) {
        if (tid < s) red[tid] += red[tid + s];
        __syncthreads();
    }
    float inv = 1.0f / red[0];
    #pragma unroll
    for (int m = 0; m < 4; ++m) {
        int cc = tid + 256 * m;
        if (cc < NCLS) out[(size_t)b * NCLS + cc] = v[m] * inv;
    }
}

extern "C" void kernel_launch(void* const* d_in, const int* in_sizes, int n_in,
                              void* d_out, int out_size, void* d_ws, size_t ws_size,
                              hipStream_t stream) {
    const float* x   = (const float*)d_in[0];
    const float* Wfx = (const float*)d_in[1];
    const float* Wfh = (const float*)d_in[2];
    const float* bf_ = (const float*)d_in[3];
    const float* Wix = (const float*)d_in[4];
    const float* Wih = (const float*)d_in[5];
    const float* bi_ = (const float*)d_in[6];
    const float* Wox = (const float*)d_in[7];
    const float* Woh = (const float*)d_in[8];
    const float* bo_ = (const float*)d_in[9];
    const float* Wcx = (const float*)d_in[10];
    const float* bc_ = (const float*)d_in[11];
    const float* Wp  = (const float*)d_in[12];
    const float* bp  = (const float*)d_in[13];

    char* ws = (char*)d_ws;
    bf16*  WhPK = (bf16*)(ws + OFF_WHPK);
    bf16*  WxPK = (bf16*)(ws + OFF_WXPK);
    float* bias = (float*)(ws + OFF_BIAS);
    bf16*  hpk0 = (bf16*)(ws + OFF_HPK0);
    bf16*  hpk1 = (bf16*)(ws + OFF_HPK1);
    bf16*  hfin = (bf16*)(ws + OFF_HFIN);
    int*   flags= (int*)(ws + OFF_FLAGS);
    bf16*  xT   = (bf16*)(ws + OFF_XT);
    float* lg   = (float*)(ws + OFF_LG);   // aliases WhPK (dead after scan)

    (void)hipFuncSetAttribute((const void*)lstm_persist<true>,
                              hipFuncAttributeMaxDynamicSharedMemorySize, 98304);
    (void)hipFuncSetAttribute((const void*)lstm_persist<false>,
                              hipFuncAttributeMaxDynamicSharedMemorySize, 98304);

    init_state<<<256, 256, 0, stream>>>((int*)hpk0, flags);
    pack_wh<<<3 * 16 * 16, 256, 0, stream>>>(Wfh, Wih, Woh, WhPK);
    pack_wx<<<4 * 16 * 8, 256, 0, stream>>>(Wfx, Wix, Wox, Wcx, WxPK);
    pack_bias<<<16, 256, 0, stream>>>(bf_, bi_, bo_, bc_, bias);

    const bool big = (ws_size >= (size_t)WS_BIG);
    if (big) {
        conv_xT<<<(BB * TT * II) / (8 * 256), 256, 0, stream>>>(x, xT);
        lstm_persist<true><<<NBLK, 512, 98304, stream>>>(x, xT, WhPK, WxPK, bias,
                                                         hpk0, hpk1, hfin, flags);
    } else {
        lstm_persist<false><<<NBLK, 512, 98304, stream>>>(x, xT, WhPK, WxPK, bias,
                                                          hpk0, hpk1, hfin, flags);
    }

    logits_kernel<<<BB / 8, 256, 0, stream>>>(hfin, Wp, bp, lg);
    softmax_kernel<<<BB, 256, 0, stream>>>(lg, (float*)d_out);
}

// Round 5
// 6017.252 us; speedup vs baseline: 1.2765x; 1.1156x over previous
//
#include <hip/hip_runtime.h>
#include <math.h>

#define TT 256
#define BB 128
#define II 512
#define HH 1024
#define NCLS 1000
#define NBLK 64           // persistent blocks (= h-col chunks)
#define CPB 16            // h-cols per block

typedef __bf16 bf16;
typedef bf16 bf16x8 __attribute__((ext_vector_type(8)));
typedef float f32x4 __attribute__((ext_vector_type(4)));
typedef int i32x4 __attribute__((ext_vector_type(4)));

#define AT_LD_I32(p) __hip_atomic_load((p), __ATOMIC_RELAXED, __HIP_MEMORY_SCOPE_AGENT)
#define AT_ST_U32(p, v) __hip_atomic_store((p), (v), __ATOMIC_RELAXED, __HIP_MEMORY_SCOPE_AGENT)

// ---------------- ws layout (bytes) ----------------
#define OFF_WHPK   0u            // 64*48*1024*2 = 6,291,456   (dead after scan)
#define OFF_LG     0u            // logits alias WhPK (post-scan only)
#define OFF_WXPK   6291456u      // 64*64*512*2  = 4,194,304
#define OFF_BIAS   10485760u     // 16,384
#define OFF_HPK0   10502144u     // 262,144   h ping  [chunk][row][16] bf16
#define OFF_HPK1   10764288u     // 262,144   h pong
#define OFF_HFIN   11026432u     // 262,144   final h, row-major [b][1024]
#define OFF_CNT    11288576u     // 33,024    cnt[(2t+g)*16], 64B stride per word
#define OFF_XT     11321600u     // 33,554,432  xT[t][b][i] bf16
#define WS_BIG     44876032u

#define LDS_WH     98304
#define LDS_TOTAL  100352        // + gdone[2][256] ints

// ---------------- init: zero h0 (hpk0) and counters ----------------
__global__ void init_state(int* __restrict__ hpk0i, int* __restrict__ cnt) {
    int idx = blockIdx.x * 256 + threadIdx.x;
    if (idx < 65536) hpk0i[idx] = 0;          // 256 KB of zeros
    if (idx < 8256) cnt[idx] = 0;
}

// ---------------- pack W_h -> WhPK[bid][g*16+c][k], g in {f,i,o} ----------------
__global__ void pack_wh(const float* __restrict__ Wfh, const float* __restrict__ Wih,
                        const float* __restrict__ Woh, bf16* __restrict__ WhPK) {
    int blk = blockIdx.x;                 // 3 * 16 * 16
    int g = blk / 256, rem = blk % 256;
    int ht = rem / 16, kt = rem % 16;
    const float* src = (g == 0) ? Wfh : (g == 1) ? Wih : Woh;
    __shared__ bf16 tile[64][72];
    int tid = threadIdx.x;
    for (int i = tid; i < 4096; i += 256) {
        int kr = i >> 6, hc = i & 63;
        tile[kr][hc] = (bf16)src[(size_t)(kt * 64 + kr) * HH + ht * 64 + hc];
    }
    __syncthreads();
    for (int i = tid; i < 4096; i += 256) {
        int hc = i >> 6, kr = i & 63;
        int h = ht * 64 + hc, bid = h >> 4, c = h & 15;
        WhPK[((size_t)bid * 48 + g * 16 + c) * 1024 + kt * 64 + kr] = tile[kr][hc];
    }
}

// ---------------- pack W_x -> WxPK[bid][g*16+c][k], g in {f,i,o,c} ----------------
__global__ void pack_wx(const float* __restrict__ Wfx, const float* __restrict__ Wix,
                        const float* __restrict__ Wox, const float* __restrict__ Wcx,
                        bf16* __restrict__ WxPK) {
    int blk = blockIdx.x;                 // 4 * 16 * 8
    int g = blk / 128, rem = blk % 128;
    int ht = rem / 8, kt = rem % 8;
    const float* src = (g == 0) ? Wfx : (g == 1) ? Wix : (g == 2) ? Wox : Wcx;
    __shared__ bf16 tile[64][72];
    int tid = threadIdx.x;
    for (int i = tid; i < 4096; i += 256) {
        int kr = i >> 6, hc = i & 63;
        tile[kr][hc] = (bf16)src[(size_t)(kt * 64 + kr) * HH + ht * 64 + hc];
    }
    __syncthreads();
    for (int i = tid; i < 4096; i += 256) {
        int hc = i >> 6, kr = i & 63;
        int h = ht * 64 + hc, bid = h >> 4, c = h & 15;
        WxPK[((size_t)bid * 64 + g * 16 + c) * 512 + kt * 64 + kr] = tile[kr][hc];
    }
}

__global__ void pack_bias(const float* __restrict__ bf_, const float* __restrict__ bi_,
                          const float* __restrict__ bo_, const float* __restrict__ bc_,
                          float* __restrict__ bias) {
    int i = blockIdx.x * 256 + threadIdx.x;
    if (i < 4 * HH) {
        int g = i >> 10, hn = i & 1023;
        const float* b = (g == 0) ? bf_ : (g == 1) ? bi_ : (g == 2) ? bo_ : bc_;
        bias[i] = b[hn];
    }
}

// ---------------- x[b][t][i] fp32 -> xT[t][b][i] bf16 ----------------
__global__ void conv_xT(const float* __restrict__ x, bf16* __restrict__ xT) {
    size_t o = ((size_t)blockIdx.x * 256 + threadIdx.x) * 8;
    int t = (int)(o >> 16);               // / (BB*II = 65536)
    int rem = (int)(o & 65535);
    int b = rem >> 9, i = rem & 511;
    const float* s = x + ((size_t)b * TT + t) * II + i;
    float4 f0 = *(const float4*)(s);
    float4 f1 = *(const float4*)(s + 4);
    bf16x8 v;
    v[0]=(bf16)f0.x; v[1]=(bf16)f0.y; v[2]=(bf16)f0.z; v[3]=(bf16)f0.w;
    v[4]=(bf16)f1.x; v[5]=(bf16)f1.y; v[6]=(bf16)f1.z; v[7]=(bf16)f1.w;
    *(bf16x8*)(xT + o) = v;
}

__device__ __forceinline__ float sigm(float x) {
    return 1.0f / (1.0f + __expf(-x));
}
__device__ __forceinline__ float tanh_f(float x) {
    float e = __expf(-2.0f * fabsf(x));
    float t = (1.0f - e) / (1.0f + e);
    return copysignf(t, x);
}

// ---------------- persistent recurrent kernel ----------------
// 64 blocks x 512 threads. TWO independent gangs per block:
//   gang 0 = waves 0-3 (batch rows 0-63), gang 1 = waves 4-7 (rows 64-127).
// Batch rows are independent LSTM chains -> gangs sync independently via
// per-step single-word counters cnt[(2t+g)*16] (0->64, device atomicAdd).
// NO __syncthreads in the t-loop. SIMD s hosts one wave of each gang, so
// one gang's poll stall overlaps the other gang's MFMA.
// Wh (f,i,o) in 96KB LDS (XOR-swizzled, read-only after staging).
template<bool XB>
__global__ __launch_bounds__(512, 1) void lstm_persist(
    const float* __restrict__ xf, const bf16* __restrict__ xT,
    const bf16* __restrict__ WhPK, const bf16* __restrict__ WxPK,
    const float* __restrict__ bias,
    bf16* __restrict__ hpk0, bf16* __restrict__ hpk1,
    bf16* __restrict__ hfin, int* __restrict__ cnt) {
    extern __shared__ char lds[];
    int* gdone = (int*)(lds + LDS_WH);     // [2][256] per-step gang counters
    const int tid = threadIdx.x, w = tid >> 6, lane = tid & 63;
    const int bid = blockIdx.x, n0 = bid * CPB;
    const int g = w >> 2, wl = w & 3;

    // ---- stage Wh slice into LDS (48 rows x 2048B, swizzle ^((r&15)<<4)) ----
    for (int i = tid; i < 48 * 128; i += 512) {
        int r = i >> 7, c8 = i & 127;
        bf16x8 v = *(const bf16x8*)(WhPK + ((size_t)bid * 48 + r) * 1024 + c8 * 8);
        int byte = (r * 2048 + c8 * 16) ^ ((r & 15) << 4);
        *(bf16x8*)(lds + byte) = v;
    }
    gdone[tid] = 0;                        // 512 ints, one per thread
    __syncthreads();

    const int lr = lane & 15;
    const int lkq = lane >> 4;
    const int lk = lkq * 8;
    const int rb = lkq * 4;
    const int row = g * 64 + wl * 16 + lr;   // batch row this lane loads
    const int hcol = n0 + lr;
    const float bbf = bias[0 * HH + hcol];
    const float bbi = bias[1 * HH + hcol];
    const float bbo = bias[2 * HH + hcol];
    const float bbc = bias[3 * HH + hcol];
    float creg[4] = {0.f, 0.f, 0.f, 0.f};
    const int hvoff = (lkq >> 1) * 4096 + row * 32 + (lk & 8) * 2;

    if (g == 1) __builtin_amdgcn_s_sleep(100);   // ~2.7us anti-phase skew

    for (int t = 0; t < TT; ++t) {
        f32x4 acc[4] = {};               // f,i,o,c

        // ---- x-part (K=512), independent of h_t ----
        #pragma unroll 4
        for (int kk = 0; kk < 16; ++kk) {
            const int k0 = kk * 32 + lk;
            bf16x8 a;
            if (XB) {
                a = *(const bf16x8*)(xT + ((size_t)t * BB + row) * II + k0);
            } else {
                const float* s = xf + ((size_t)row * TT + t) * II + k0;
                float4 f0 = *(const float4*)s, f1 = *(const float4*)(s + 4);
                a[0]=(bf16)f0.x; a[1]=(bf16)f0.y; a[2]=(bf16)f0.z; a[3]=(bf16)f0.w;
                a[4]=(bf16)f1.x; a[5]=(bf16)f1.y; a[6]=(bf16)f1.z; a[7]=(bf16)f1.w;
            }
            #pragma unroll
            for (int tau = 0; tau < 4; ++tau) {
                bf16x8 b = *(const bf16x8*)(WxPK + ((size_t)bid * 64 + tau * 16 + lr) * 512 + k0);
                acc[tau] = __builtin_amdgcn_mfma_f32_16x16x32_bf16(a, b, acc[tau], 0, 0, 0);
            }
        }

        if (t > 0) {                     // t=0: h0=0, skip wait and h-GEMM
            // ---- wait for h_t of my gang (single-word, per-step address) ----
            const int* cw = cnt + (2 * t + g) * 16;
            while (AT_LD_I32(cw) < NBLK) __builtin_amdgcn_s_sleep(4);
            asm volatile("s_waitcnt vmcnt(0)" ::: "memory");
            __builtin_amdgcn_sched_barrier(0);

            // ---- h-part: 2 passes x 16 pipelined coherent dwordx4 loads ----
            const char* hbase = (const char*)((t & 1) ? hpk1 : hpk0);
            #pragma unroll
            for (int p = 0; p < 2; ++p) {
                i32x4 hv[16];
                #pragma unroll
                for (int q = 0; q < 16; ++q) {
                    const void* ptr = hbase + hvoff + (p * 16 + q) * 8192;
                    asm volatile("global_load_dwordx4 %0, %1, off sc0 sc1"
                                 : "=v"(hv[q]) : "v"(ptr) : "memory");
                }
                #pragma unroll
                for (int half = 0; half < 2; ++half) {
                    if (half == 0) asm volatile("s_waitcnt vmcnt(8)" ::: "memory");
                    else           asm volatile("s_waitcnt vmcnt(0)" ::: "memory");
                    __builtin_amdgcn_sched_barrier(0);
                    #pragma unroll
                    for (int q = half * 8; q < half * 8 + 8; ++q) {
                        const int k0 = (p * 16 + q) * 32 + lk;
                        bf16x8 a = __builtin_bit_cast(bf16x8, hv[q]);
                        #pragma unroll
                        for (int tau = 0; tau < 3; ++tau) {   // c-gate: x-only
                            const int r = tau * 16 + lr;
                            bf16x8 b = *(const bf16x8*)(lds + ((r * 2048 + k0 * 2) ^ ((r & 15) << 4)));
                            acc[tau] = __builtin_amdgcn_mfma_f32_16x16x32_bf16(a, b, acc[tau], 0, 0, 0);
                        }
                    }
                    __builtin_amdgcn_sched_barrier(0);
                }
            }
        }

        // ---- pointwise (thread-local), h_{t+1} -> hpk[(t+1)&1] ----
        bf16* hout = (t & 1) ? hpk0 : hpk1;
        #pragma unroll
        for (int j = 0; j < 4; ++j) {
            const int row_o = g * 64 + wl * 16 + rb + j;
            float pf = acc[0][j] + bbf;
            float pi = acc[1][j] + bbi;
            float po = acc[2][j] + bbo;
            float pc = acc[3][j] + bbc;
            float fg = sigm(pf), ig = sigm(pi), og = sigm(po);
            float cn = tanh_f(pc) * ig + creg[j] * fg;
            creg[j] = cn;
            union { bf16 h; unsigned short u; } cv;
            cv.h = (bf16)(tanh_f(cn) * og);
            unsigned int mine  = (unsigned int)cv.u;
            unsigned int other = (unsigned int)__shfl_xor((int)mine, 1);
            if (!(lane & 1)) {
                unsigned int word = mine | (other << 16);
                AT_ST_U32((unsigned int*)(hout + ((size_t)bid * 128 + row_o) * 16 + (lr & 14)), word);
            }
            if (t == TT - 1) hfin[(size_t)row_o * HH + hcol] = cv.h;
        }
        // drain my stores, then gang-complete protocol (no __syncthreads)
        asm volatile("s_waitcnt vmcnt(0)" ::: "memory");
        __builtin_amdgcn_sched_barrier(0);
        if (lane == 0) {
            int old = atomicAdd(&gdone[g * 256 + t], 1);
            if (old == 3)                     // last wave of my gang in this block
                atomicAdd(cnt + (2 * (t + 1) + g) * 16, 1);
        }
    }
}

// ---------------- head: logits = h @ W_ph + b_p ----------------
__global__ __launch_bounds__(256) void logits_kernel(
    const bf16* __restrict__ h, const float* __restrict__ Wp,
    const float* __restrict__ bp, float* __restrict__ out) {
    const int tid = threadIdx.x;
    const int r0  = blockIdx.x * 8;
    __shared__ float hs[8][HH];
    for (int i = tid; i < 8 * HH; i += 256)
        hs[i >> 10][i & 1023] = (float)h[(size_t)(r0 + (i >> 10)) * HH + (i & 1023)];
    __syncthreads();
    float acc[8][4] = {};
    for (int k = 0; k < HH; ++k) {
        float w[4];
        #pragma unroll
        for (int m = 0; m < 4; ++m) {
            int cc = tid + 256 * m;
            w[m] = (cc < NCLS) ? Wp[(size_t)k * NCLS + cc] : 0.0f;
        }
        #pragma unroll
        for (int r = 0; r < 8; ++r) {
            float hv = hs[r][k];
            #pragma unroll
            for (int m = 0; m < 4; ++m) acc[r][m] += hv * w[m];
        }
    }
    #pragma unroll
    for (int r = 0; r < 8; ++r) {
        #pragma unroll
        for (int m = 0; m < 4; ++m) {
            int cc = tid + 256 * m;
            if (cc < NCLS) out[(size_t)(r0 + r) * NCLS + cc] = acc[r][m] + bp[cc];
        }
    }
}

// ---------------- softmax over C=1000 per row ----------------
__global__ __launch_bounds__(256) void softmax_kernel(const float* __restrict__ logits,
                                                      float* __restrict__ out) {
    const int b = blockIdx.x, tid = threadIdx.x;
    __shared__ float red[256];
    float v[4];
    float mx = -1e30f;
    #pragma unroll
    for (int m = 0; m < 4; ++m) {
        int cc = tid + 256 * m;
        v[m] = (cc < NCLS) ? logits[(size_t)b * NCLS + cc] : -1e30f;
        mx = fmaxf(mx, v[m]);
    }
    red[tid] = mx; __syncthreads();
    for (int s = 128; s > 0; s >>= 1) {
        if (tid < s) red[tid] = fmaxf(red[tid], red[tid + s]);
        __syncthreads();
    }
    mx = red[0]; __syncthreads();
    float sum = 0.0f;
    #pragma unroll
    for (int m = 0; m < 4; ++m) {
        int cc = tid + 256 * m;
        if (cc < NCLS) { v[m] = __expf(v[m] - mx); sum += v[m]; }
    }
    red[tid] = sum; __syncthreads();
    for (int s = 128; s > 0; s >>= 1) {
        if (tid < s) red[tid] += red[tid + s];
        __syncthreads();
    }
    float inv = 1.0f / red[0];
    #pragma unroll
    for (int m = 0; m < 4; ++m) {
        int cc = tid + 256 * m;
        if (cc < NCLS) out[(size_t)b * NCLS + cc] = v[m] * inv;
    }
}

extern "C" void kernel_launch(void* const* d_in, const int* in_sizes, int n_in,
                              void* d_out, int out_size, void* d_ws, size_t ws_size,
                              hipStream_t stream) {
    const float* x   = (const float*)d_in[0];
    const float* Wfx = (const float*)d_in[1];
    const float* Wfh = (const float*)d_in[2];
    const float* bf_ = (const float*)d_in[3];
    const float* Wix = (const float*)d_in[4];
    const float* Wih = (const float*)d_in[5];
    const float* bi_ = (const float*)d_in[6];
    const float* Wox = (const float*)d_in[7];
    const float* Woh = (const float*)d_in[8];
    const float* bo_ = (const float*)d_in[9];
    const float* Wcx = (const float*)d_in[10];
    const float* bc_ = (const float*)d_in[11];
    const float* Wp  = (const float*)d_in[12];
    const float* bp  = (const float*)d_in[13];

    char* ws = (char*)d_ws;
    bf16*  WhPK = (bf16*)(ws + OFF_WHPK);
    bf16*  WxPK = (bf16*)(ws + OFF_WXPK);
    float* bias = (float*)(ws + OFF_BIAS);
    bf16*  hpk0 = (bf16*)(ws + OFF_HPK0);
    bf16*  hpk1 = (bf16*)(ws + OFF_HPK1);
    bf16*  hfin = (bf16*)(ws + OFF_HFIN);
    int*   cnt  = (int*)(ws + OFF_CNT);
    bf16*  xT   = (bf16*)(ws + OFF_XT);
    float* lg   = (float*)(ws + OFF_LG);   // aliases WhPK (dead after scan)

    (void)hipFuncSetAttribute((const void*)lstm_persist<true>,
                              hipFuncAttributeMaxDynamicSharedMemorySize, LDS_TOTAL);
    (void)hipFuncSetAttribute((const void*)lstm_persist<false>,
                              hipFuncAttributeMaxDynamicSharedMemorySize, LDS_TOTAL);

    init_state<<<256, 256, 0, stream>>>((int*)hpk0, cnt);
    pack_wh<<<3 * 16 * 16, 256, 0, stream>>>(Wfh, Wih, Woh, WhPK);
    pack_wx<<<4 * 16 * 8, 256, 0, stream>>>(Wfx, Wix, Wox, Wcx, WxPK);
    pack_bias<<<16, 256, 0, stream>>>(bf_, bi_, bo_, bc_, bias);

    const bool big = (ws_size >= (size_t)WS_BIG);
    if (big) {
        conv_xT<<<(BB * TT * II) / (8 * 256), 256, 0, stream>>>(x, xT);
        lstm_persist<true><<<NBLK, 512, LDS_TOTAL, stream>>>(x, xT, WhPK, WxPK, bias,
                                                             hpk0, hpk1, hfin, cnt);
    } else {
        lstm_persist<false><<<NBLK, 512, LDS_TOTAL, stream>>>(x, xT, WhPK, WxPK, bias,
                                                              hpk0, hpk1, hfin, cnt);
    }

    logits_kernel<<<BB / 8, 256, 0, stream>>>(hfin, Wp, bp, lg);
    softmax_kernel<<<BB, 256, 0, stream>>>(lg, (float*)d_out);
}

// Round 8
// 5996.020 us; speedup vs baseline: 1.2810x; 1.0035x over previous
//
#include <hip/hip_runtime.h>
#include <math.h>

#define TT 256
#define BB 128
#define II 512
#define HH 1024
#define NCLS 1000
#define NBLK 64           // persistent blocks (= h-col chunks)
#define CPB 16            // h-cols per block

typedef __bf16 bf16;
typedef bf16 bf16x8 __attribute__((ext_vector_type(8)));
typedef float f32x4 __attribute__((ext_vector_type(4)));
typedef int i32x4 __attribute__((ext_vector_type(4)));

#define AT_LD_I32(p) __hip_atomic_load((p), __ATOMIC_RELAXED, __HIP_MEMORY_SCOPE_AGENT)
#define AT_ST_U32(p, v) __hip_atomic_store((p), (v), __ATOMIC_RELAXED, __HIP_MEMORY_SCOPE_AGENT)

// ---------------- ws layout (bytes) ----------------
#define OFF_WHPK   0u            // 64*48*1024*2 = 6,291,456   (dead after scan)
#define OFF_LG     0u            // logits alias WhPK (post-scan only)
#define OFF_WXPK   6291456u      // 64*64*512*2  = 4,194,304
#define OFF_BIAS   10485760u     // 16,384
#define OFF_HPK0   10502144u     // 262,144   h ping  [chunk][row][16] bf16
#define OFF_HPK1   10764288u     // 262,144   h pong
#define OFF_HFIN   11026432u     // 262,144   final h, row-major [b][1024]
#define OFF_CNT    11288576u     // monotonic subcounters: (g*8+j)*32 ints, 128B stride
#define OFF_XT     11321600u     // 33,554,432  xT[t][b][i] bf16
#define WS_BIG     44876032u

#define LDS_WH     98304
#define LDS_GD     98304         // gdone[2][256] ints (2KB)
#define LDS_GF     100352        // gangflag[2] ints
#define LDS_TOTAL  100416

// ---------------- init: zero h0 (hpk0) and counters ----------------
__global__ void init_state(int* __restrict__ hpk0i, int* __restrict__ cnt) {
    int idx = blockIdx.x * 256 + threadIdx.x;
    if (idx < 65536) hpk0i[idx] = 0;          // 256 KB of zeros
    if (idx < 8256) cnt[idx] = 0;
}

// ---------------- pack W_h -> WhPK[bid][g*16+c][k], g in {f,i,o} ----------------
__global__ void pack_wh(const float* __restrict__ Wfh, const float* __restrict__ Wih,
                        const float* __restrict__ Woh, bf16* __restrict__ WhPK) {
    int blk = blockIdx.x;                 // 3 * 16 * 16
    int g = blk / 256, rem = blk % 256;
    int ht = rem / 16, kt = rem % 16;
    const float* src = (g == 0) ? Wfh : (g == 1) ? Wih : Woh;
    __shared__ bf16 tile[64][72];
    int tid = threadIdx.x;
    for (int i = tid; i < 4096; i += 256) {
        int kr = i >> 6, hc = i & 63;
        tile[kr][hc] = (bf16)src[(size_t)(kt * 64 + kr) * HH + ht * 64 + hc];
    }
    __syncthreads();
    for (int i = tid; i < 4096; i += 256) {
        int hc = i >> 6, kr = i & 63;
        int h = ht * 64 + hc, bid = h >> 4, c = h & 15;
        WhPK[((size_t)bid * 48 + g * 16 + c) * 1024 + kt * 64 + kr] = tile[kr][hc];
    }
}

// ---------------- pack W_x -> WxPK[bid][g*16+c][k], g in {f,i,o,c} ----------------
__global__ void pack_wx(const float* __restrict__ Wfx, const float* __restrict__ Wix,
                        const float* __restrict__ Wox, const float* __restrict__ Wcx,
                        bf16* __restrict__ WxPK) {
    int blk = blockIdx.x;                 // 4 * 16 * 8
    int g = blk / 128, rem = blk % 128;
    int ht = rem / 8, kt = rem % 8;
    const float* src = (g == 0) ? Wfx : (g == 1) ? Wix : (g == 2) ? Wox : Wcx;
    __shared__ bf16 tile[64][72];
    int tid = threadIdx.x;
    for (int i = tid; i < 4096; i += 256) {
        int kr = i >> 6, hc = i & 63;
        tile[kr][hc] = (bf16)src[(size_t)(kt * 64 + kr) * HH + ht * 64 + hc];
    }
    __syncthreads();
    for (int i = tid; i < 4096; i += 256) {
        int hc = i >> 6, kr = i & 63;
        int h = ht * 64 + hc, bid = h >> 4, c = h & 15;
        WxPK[((size_t)bid * 64 + g * 16 + c) * 512 + kt * 64 + kr] = tile[kr][hc];
    }
}

__global__ void pack_bias(const float* __restrict__ bf_, const float* __restrict__ bi_,
                          const float* __restrict__ bo_, const float* __restrict__ bc_,
                          float* __restrict__ bias) {
    int i = blockIdx.x * 256 + threadIdx.x;
    if (i < 4 * HH) {
        int g = i >> 10, hn = i & 1023;
        const float* b = (g == 0) ? bf_ : (g == 1) ? bi_ : (g == 2) ? bo_ : bc_;
        bias[i] = b[hn];
    }
}

// ---------------- x[b][t][i] fp32 -> xT[t][b][i] bf16 ----------------
__global__ void conv_xT(const float* __restrict__ x, bf16* __restrict__ xT) {
    size_t o = ((size_t)blockIdx.x * 256 + threadIdx.x) * 8;
    int t = (int)(o >> 16);               // / (BB*II = 65536)
    int rem = (int)(o & 65535);
    int b = rem >> 9, i = rem & 511;
    const float* s = x + ((size_t)b * TT + t) * II + i;
    float4 f0 = *(const float4*)(s);
    float4 f1 = *(const float4*)(s + 4);
    bf16x8 v;
    v[0]=(bf16)f0.x; v[1]=(bf16)f0.y; v[2]=(bf16)f0.z; v[3]=(bf16)f0.w;
    v[4]=(bf16)f1.x; v[5]=(bf16)f1.y; v[6]=(bf16)f1.z; v[7]=(bf16)f1.w;
    *(bf16x8*)(xT + o) = v;
}

__device__ __forceinline__ float sigm(float x) {
    return 1.0f / (1.0f + __expf(-x));
}
__device__ __forceinline__ float tanh_f(float x) {
    float e = __expf(-2.0f * fabsf(x));
    float t = (1.0f - e) / (1.0f + e);
    return copysignf(t, x);
}

// ---------------- persistent recurrent kernel ----------------
// 64 blocks x 512 threads. TWO independent gangs per block:
//   gang 0 = waves 0-3 (batch rows 0-63), gang 1 = waves 4-7 (rows 64-127).
// Sync per gang per step: producers -> one atomicAdd per block into an
// 8-way-striped MONOTONIC subcounter (bid&7; 128B apart; value hits 8*(t+1)
// when all 8 of its blocks finish step t). Consumer side: ONE poller wave
// per gang polls the 8 words with ~1us s_sleep backoff (kills the
// read-hammer that serialized producers' RMWs in R2-R4), then broadcasts
// via an LDS flag to the gang's other 3 waves. No __syncthreads in t-loop.
// Wh (f,i,o) in 96KB LDS (XOR-swizzled); h via pipelined sc0sc1 loads.
template<bool XB>
__global__ __launch_bounds__(512, 1) void lstm_persist(
    const float* __restrict__ xf, const bf16* __restrict__ xT,
    const bf16* __restrict__ WhPK, const bf16* __restrict__ WxPK,
    const float* __restrict__ bias,
    bf16* __restrict__ hpk0, bf16* __restrict__ hpk1,
    bf16* __restrict__ hfin, int* __restrict__ cnt) {
    extern __shared__ char lds[];
    int* gdone = (int*)(lds + LDS_GD);     // [2][256] per-step gang wave-counters
    volatile int* gflag = (volatile int*)(lds + LDS_GF);  // [2] gang step flags
    const int tid = threadIdx.x, w = tid >> 6, lane = tid & 63;
    const int bid = blockIdx.x, n0 = bid * CPB;
    const int g = w >> 2, wl = w & 3;

    // ---- stage Wh slice into LDS (48 rows x 2048B, swizzle ^((r&15)<<4)) ----
    for (int i = tid; i < 48 * 128; i += 512) {
        int r = i >> 7, c8 = i & 127;
        bf16x8 v = *(const bf16x8*)(WhPK + ((size_t)bid * 48 + r) * 1024 + c8 * 8);
        int byte = (r * 2048 + c8 * 16) ^ ((r & 15) << 4);
        *(bf16x8*)(lds + byte) = v;
    }
    gdone[tid] = 0;                        // 512 ints, one per thread
    if (tid < 2) gflag[tid] = 0;
    __syncthreads();

    const int lr = lane & 15;
    const int lkq = lane >> 4;
    const int lk = lkq * 8;
    const int rb = lkq * 4;
    const int row = g * 64 + wl * 16 + lr;   // batch row this lane loads
    const int hcol = n0 + lr;
    const float bbf = bias[0 * HH + hcol];
    const float bbi = bias[1 * HH + hcol];
    const float bbo = bias[2 * HH + hcol];
    const float bbc = bias[3 * HH + hcol];
    float creg[4] = {0.f, 0.f, 0.f, 0.f};
    const int hvoff = (lkq >> 1) * 4096 + row * 32 + (lk & 8) * 2;
    // poller: lanes 0..7 watch the 8 subcounters of this gang (128B apart)
    const int* cw = cnt + (g * 8 + (lane < 8 ? lane : 7)) * 32;

    if (g == 1) __builtin_amdgcn_s_sleep(100);   // ~2.7us anti-phase skew

    for (int t = 0; t < TT; ++t) {
        f32x4 acc[4] = {};               // f,i,o,c

        // ---- x-part (K=512), independent of h_t ----
        #pragma unroll 4
        for (int kk = 0; kk < 16; ++kk) {
            const int k0 = kk * 32 + lk;
            bf16x8 a;
            if (XB) {
                a = *(const bf16x8*)(xT + ((size_t)t * BB + row) * II + k0);
            } else {
                const float* s = xf + ((size_t)row * TT + t) * II + k0;
                float4 f0 = *(const float4*)s, f1 = *(const float4*)(s + 4);
                a[0]=(bf16)f0.x; a[1]=(bf16)f0.y; a[2]=(bf16)f0.z; a[3]=(bf16)f0.w;
                a[4]=(bf16)f1.x; a[5]=(bf16)f1.y; a[6]=(bf16)f1.z; a[7]=(bf16)f1.w;
            }
            #pragma unroll
            for (int tau = 0; tau < 4; ++tau) {
                bf16x8 b = *(const bf16x8*)(WxPK + ((size_t)bid * 64 + tau * 16 + lr) * 512 + k0);
                acc[tau] = __builtin_amdgcn_mfma_f32_16x16x32_bf16(a, b, acc[tau], 0, 0, 0);
            }
        }

        if (t > 0) {                     // t=0: h0=0, skip wait and h-GEMM
            // ---- wait for h_t of my gang: poller wave + LDS broadcast ----
            if (wl == 0) {
                const int need = 8 * t;
                while (true) {
                    int v = AT_LD_I32(cw);
                    if (__all((lane >= 8) || (v >= need))) break;
                    __builtin_amdgcn_s_sleep(16);   // ~1us backoff
                }
                asm volatile("" ::: "memory");
                gflag[g] = t;
            } else {
                while (gflag[g] < t) __builtin_amdgcn_s_sleep(1);
            }
            asm volatile("s_waitcnt vmcnt(0) lgkmcnt(0)" ::: "memory");
            __builtin_amdgcn_sched_barrier(0);

            // ---- h-part: 2 passes x 16 pipelined coherent dwordx4 loads ----
            const char* hbase = (const char*)((t & 1) ? hpk1 : hpk0);
            #pragma unroll
            for (int p = 0; p < 2; ++p) {
                i32x4 hv[16];
                #pragma unroll
                for (int q = 0; q < 16; ++q) {
                    const void* ptr = hbase + hvoff + (p * 16 + q) * 8192;
                    asm volatile("global_load_dwordx4 %0, %1, off sc0 sc1"
                                 : "=v"(hv[q]) : "v"(ptr) : "memory");
                }
                #pragma unroll
                for (int half = 0; half < 2; ++half) {
                    if (half == 0) asm volatile("s_waitcnt vmcnt(8)" ::: "memory");
                    else           asm volatile("s_waitcnt vmcnt(0)" ::: "memory");
                    __builtin_amdgcn_sched_barrier(0);
                    #pragma unroll
                    for (int q = half * 8; q < half * 8 + 8; ++q) {
                        const int k0 = (p * 16 + q) * 32 + lk;
                        bf16x8 a = __builtin_bit_cast(bf16x8, hv[q]);
                        #pragma unroll
                        for (int tau = 0; tau < 3; ++tau) {   // c-gate: x-only
                            const int r = tau * 16 + lr;
                            bf16x8 b = *(const bf16x8*)(lds + ((r * 2048 + k0 * 2) ^ ((r & 15) << 4)));
                            acc[tau] = __builtin_amdgcn_mfma_f32_16x16x32_bf16(a, b, acc[tau], 0, 0, 0);
                        }
                    }
                    __builtin_amdgcn_sched_barrier(0);
                }
            }
        }

        // ---- pointwise (thread-local), h_{t+1} -> hpk[(t+1)&1] ----
        bf16* hout = (t & 1) ? hpk0 : hpk1;
        #pragma unroll
        for (int j = 0; j < 4; ++j) {
            const int row_o = g * 64 + wl * 16 + rb + j;
            float pf = acc[0][j] + bbf;
            float pi = acc[1][j] + bbi;
            float po = acc[2][j] + bbo;
            float pc = acc[3][j] + bbc;
            float fg = sigm(pf), ig = sigm(pi), og = sigm(po);
            float cn = tanh_f(pc) * ig + creg[j] * fg;
            creg[j] = cn;
            union { bf16 h; unsigned short u; } cv;
            cv.h = (bf16)(tanh_f(cn) * og);
            unsigned int mine  = (unsigned int)cv.u;
            unsigned int other = (unsigned int)__shfl_xor((int)mine, 1);
            if (!(lane & 1)) {
                unsigned int word = mine | (other << 16);
                AT_ST_U32((unsigned int*)(hout + ((size_t)bid * 128 + row_o) * 16 + (lr & 14)), word);
            }
            if (t == TT - 1) hfin[(size_t)row_o * HH + hcol] = cv.h;
        }
        // drain my stores, then gang-complete protocol (no __syncthreads)
        asm volatile("s_waitcnt vmcnt(0)" ::: "memory");
        __builtin_amdgcn_sched_barrier(0);
        if (lane == 0) {
            int old = atomicAdd(&gdone[g * 256 + t], 1);
            if (old == 3)                     // last wave of my gang in this block
                atomicAdd((int*)(cnt + (g * 8 + (bid & 7)) * 32), 1);
        }
    }
}

// ---------------- head: logits = h @ W_ph + b_p ----------------
__global__ __launch_bounds__(256) void logits_kernel(
    const bf16* __restrict__ h, const float* __restrict__ Wp,
    const float* __restrict__ bp, float* __restrict__ out) {
    const int tid = threadIdx.x;
    const int r0  = blockIdx.x * 8;
    __shared__ float hs[8][HH];
    for (int i = tid; i < 8 * HH; i += 256)
        hs[i >> 10][i & 1023] = (float)h[(size_t)(r0 + (i >> 10)) * HH + (i & 1023)];
    __syncthreads();
    float acc[8][4] = {};
    for (int k = 0; k < HH; ++k) {
        float w[4];
        #pragma unroll
        for (int m = 0; m < 4; ++m) {
            int cc = tid + 256 * m;
            w[m] = (cc < NCLS) ? Wp[(size_t)k * NCLS + cc] : 0.0f;
        }
        #pragma unroll
        for (int r = 0; r < 8; ++r) {
            float hv = hs[r][k];
            #pragma unroll
            for (int m = 0; m < 4; ++m) acc[r][m] += hv * w[m];
        }
    }
    #pragma unroll
    for (int r = 0; r < 8; ++r) {
        #pragma unroll
        for (int m = 0; m < 4; ++m) {
            int cc = tid + 256 * m;
            if (cc < NCLS) out[(size_t)(r0 + r) * NCLS + cc] = acc[r][m] + bp[cc];
        }
    }
}

// ---------------- softmax over C=1000 per row ----------------
__global__ __launch_bounds__(256) void softmax_kernel(const float* __restrict__ logits,
                                                      float* __restrict__ out) {
    const int b = blockIdx.x, tid = threadIdx.x;
    __shared__ float red[256];
    float v[4];
    float mx = -1e30f;
    #pragma unroll
    for (int m = 0; m < 4; ++m) {
        int cc = tid + 256 * m;
        v[m] = (cc < NCLS) ? logits[(size_t)b * NCLS + cc] : -1e30f;
        mx = fmaxf(mx, v[m]);
    }
    red[tid] = mx; __syncthreads();
    for (int s = 128; s > 0; s >>= 1) {
        if (tid < s) red[tid] = fmaxf(red[tid], red[tid + s]);
        __syncthreads();
    }
    mx = red[0]; __syncthreads();
    float sum = 0.0f;
    #pragma unroll
    for (int m = 0; m < 4; ++m) {
        int cc = tid + 256 * m;
        if (cc < NCLS) { v[m] = __expf(v[m] - mx); sum += v[m]; }
    }
    red[tid] = sum; __syncthreads();
    for (int s = 128; s > 0; s >>= 1) {
        if (tid < s) red[tid] += red[tid + s];
        __syncthreads();
    }
    float inv = 1.0f / red[0];
    #pragma unroll
    for (int m = 0; m < 4; ++m) {
        int cc = tid + 256 * m;
        if (cc < NCLS) out[(size_t)b * NCLS + cc] = v[m] * inv;
    }
}

extern "C" void kernel_launch(void* const* d_in, const int* in_sizes, int n_in,
                              void* d_out, int out_size, void* d_ws, size_t ws_size,
                              hipStream_t stream) {
    const float* x   = (const float*)d_in[0];
    const float* Wfx = (const float*)d_in[1];
    const float* Wfh = (const float*)d_in[2];
    const float* bf_ = (const float*)d_in[3];
    const float* Wix = (const float*)d_in[4];
    const float* Wih = (const float*)d_in[5];
    const float* bi_ = (const float*)d_in[6];
    const float* Wox = (const float*)d_in[7];
    const float* Woh = (const float*)d_in[8];
    const float* bo_ = (const float*)d_in[9];
    const float* Wcx = (const float*)d_in[10];
    const float* bc_ = (const float*)d_in[11];
    const float* Wp  = (const float*)d_in[12];
    const float* bp  = (const float*)d_in[13];

    char* ws = (char*)d_ws;
    bf16*  WhPK = (bf16*)(ws + OFF_WHPK);
    bf16*  WxPK = (bf16*)(ws + OFF_WXPK);
    float* bias = (float*)(ws + OFF_BIAS);
    bf16*  hpk0 = (bf16*)(ws + OFF_HPK0);
    bf16*  hpk1 = (bf16*)(ws + OFF_HPK1);
    bf16*  hfin = (bf16*)(ws + OFF_HFIN);
    int*   cnt  = (int*)(ws + OFF_CNT);
    bf16*  xT   = (bf16*)(ws + OFF_XT);
    float* lg   = (float*)(ws + OFF_LG);   // aliases WhPK (dead after scan)

    (void)hipFuncSetAttribute((const void*)lstm_persist<true>,
                              hipFuncAttributeMaxDynamicSharedMemorySize, LDS_TOTAL);
    (void)hipFuncSetAttribute((const void*)lstm_persist<false>,
                              hipFuncAttributeMaxDynamicSharedMemorySize, LDS_TOTAL);

    init_state<<<256, 256, 0, stream>>>((int*)hpk0, cnt);
    pack_wh<<<3 * 16 * 16, 256, 0, stream>>>(Wfh, Wih, Woh, WhPK);
    pack_wx<<<4 * 16 * 8, 256, 0, stream>>>(Wfx, Wix, Wox, Wcx, WxPK);
    pack_bias<<<16, 256, 0, stream>>>(bf_, bi_, bo_, bc_, bias);

    const bool big = (ws_size >= (size_t)WS_BIG);
    if (big) {
        conv_xT<<<(BB * TT * II) / (8 * 256), 256, 0, stream>>>(x, xT);
        lstm_persist<true><<<NBLK, 512, LDS_TOTAL, stream>>>(x, xT, WhPK, WxPK, bias,
                                                             hpk0, hpk1, hfin, cnt);
    } else {
        lstm_persist<false><<<NBLK, 512, LDS_TOTAL, stream>>>(x, xT, WhPK, WxPK, bias,
                                                              hpk0, hpk1, hfin, cnt);
    }

    logits_kernel<<<BB / 8, 256, 0, stream>>>(hfin, Wp, bp, lg);
    softmax_kernel<<<BB, 256, 0, stream>>>(lg, (float*)d_out);
}